// Round 3
// baseline (2485.245 us; speedup 1.0000x reference)
//
#include <hip/hip_runtime.h>

typedef __bf16 bf16;
typedef __bf16 bf16x8 __attribute__((ext_vector_type(8)));
typedef _Float16 f16;
typedef _Float16 f16x8 __attribute__((ext_vector_type(8)));
typedef _Float16 f16x4 __attribute__((ext_vector_type(4)));
typedef float f32x4 __attribute__((ext_vector_type(4)));

#define TOK   2048   // B*S
#define SEQ   1024
#define HIDD  2048
#define NHEADS 16
#define QCD   1536
#define KVCD  512
#define ROPED 64
#define NOPED 128
#define QDIM  192    // NOPE+ROPE
#define VHD   128
#define KVD   576
#define KVDP  640    // padded to multiple of 128
#define INTERD 1408
#define GUD   2816   // 2*INTER (gate|up fused)
#define RMS_EPS 1e-6f
#define LSCALE 2048.0f
#define LINV   (1.0f/2048.0f)

// ---------------------------------------------------------------------------
// Transpose-convert f32: src (K,N) f32 -> dst (Npad,K) f32. Rows [N,Npad) zero.
__global__ __launch_bounds__(256) void tconvf_kernel(const float* __restrict__ src,
                                                     float* __restrict__ dst,
                                                     int K, int N, int Npad) {
    __shared__ float tile[32][33];
    int nb = blockIdx.x * 32, kb = blockIdx.y * 32;
    int tx = threadIdx.x & 31, ty = threadIdx.x >> 5;
#pragma unroll
    for (int i = 0; i < 32; i += 8) {
        int k = kb + ty + i, n = nb + tx;
        tile[ty + i][tx] = (k < K && n < N) ? src[(long)k * N + n] : 0.f;
    }
    __syncthreads();
#pragma unroll
    for (int i = 0; i < 32; i += 8) {
        int n = nb + ty + i, k = kb + tx;
        if (n < Npad && k < K) dst[(long)n * K + k] = tile[tx][ty + i];
    }
}

// Transpose-convert bf16: src (K,N) f32 -> dst (Npad,K) bf16.
__global__ __launch_bounds__(256) void tconv_kernel(const float* __restrict__ src,
                                                    bf16* __restrict__ dst,
                                                    int K, int N, int Npad) {
    __shared__ float tile[32][33];
    int nb = blockIdx.x * 32, kb = blockIdx.y * 32;
    int tx = threadIdx.x & 31, ty = threadIdx.x >> 5;
#pragma unroll
    for (int i = 0; i < 32; i += 8) {
        int k = kb + ty + i, n = nb + tx;
        tile[ty + i][tx] = (k < K && n < N) ? src[(long)k * N + n] : 0.f;
    }
    __syncthreads();
#pragma unroll
    for (int i = 0; i < 32; i += 8) {
        int n = nb + ty + i, k = kb + tx;
        if (n < Npad && k < K) dst[(long)n * K + k] = (bf16)tile[tx][ty + i];
    }
}

// ---------------------------------------------------------------------------
// Split-precision NT GEMM: C[m][n] = sum_k A[m][k]*B[n][k], A,B f32.
// Stages fp16 hi/lo planes in LDS; acc1 = Ah*Bh, acc2 = Ah*(Bl*2048)+(Al*2048)*Bh;
// result = acc1 + acc2/2048  (operand rel err ~2^-22).
// mode 0: f32 store; 2: f32 store + aux[row*auxLd+col].
__global__ __launch_bounds__(256) void gemm_f32s_kernel(
    const float* __restrict__ A, const float* __restrict__ B, float* __restrict__ C,
    const float* __restrict__ aux,
    int K, int lda, int ldb, int ldc,
    long sA, long sB, long sC,
    int mode, int auxLd)
{
    __shared__ f16 AhS[128 * 40], AlS[128 * 40], BhS[128 * 40], BlS[128 * 40];
    const int tid = threadIdx.x;
    const int bn = blockIdx.x, bm = blockIdx.y, z = blockIdx.z;
    const float* Ab = A + (long)z * sA + (long)bm * 128 * lda;
    const float* Bb = B + (long)z * sB + (long)bn * 128 * ldb;
    const int lane = tid & 63;
    const int wm = tid >> 7, wn = (tid >> 6) & 1;
    const int lr = lane & 15, lk = (lane >> 4) << 3;
    f32x4 acc1[4][4] = {};
    f32x4 acc2[4][4] = {};

    for (int k0 = 0; k0 < K; k0 += 32) {
#pragma unroll
        for (int i = 0; i < 4; i++) {
            int idx = tid + i * 256;          // 0..1023 over 128 rows x 8 f32x4
            int rr = idx >> 3, kc = (idx & 7) << 2;
            f32x4 va = *(const f32x4*)&Ab[(long)rr * lda + k0 + kc];
            f32x4 vb = *(const f32x4*)&Bb[(long)rr * ldb + k0 + kc];
            f16x4 ha, la, hb, lb;
#pragma unroll
            for (int j = 0; j < 4; j++) {
                f16 h = (f16)va[j]; ha[j] = h; la[j] = (f16)((va[j] - (float)h) * LSCALE);
                f16 g = (f16)vb[j]; hb[j] = g; lb[j] = (f16)((vb[j] - (float)g) * LSCALE);
            }
            *(f16x4*)&AhS[rr * 40 + kc] = ha; *(f16x4*)&AlS[rr * 40 + kc] = la;
            *(f16x4*)&BhS[rr * 40 + kc] = hb; *(f16x4*)&BlS[rr * 40 + kc] = lb;
        }
        __syncthreads();
        f16x8 ah[4], al[4], bh[4], bl[4];
#pragma unroll
        for (int mi = 0; mi < 4; mi++) {
            int r = (wm * 64 + mi * 16 + lr) * 40 + lk;
            ah[mi] = *(const f16x8*)&AhS[r]; al[mi] = *(const f16x8*)&AlS[r];
        }
#pragma unroll
        for (int ni = 0; ni < 4; ni++) {
            int r = (wn * 64 + ni * 16 + lr) * 40 + lk;
            bh[ni] = *(const f16x8*)&BhS[r]; bl[ni] = *(const f16x8*)&BlS[r];
        }
#pragma unroll
        for (int mi = 0; mi < 4; mi++)
#pragma unroll
            for (int ni = 0; ni < 4; ni++) {
                acc1[mi][ni] = __builtin_amdgcn_mfma_f32_16x16x32_f16(ah[mi], bh[ni], acc1[mi][ni], 0, 0, 0);
                acc2[mi][ni] = __builtin_amdgcn_mfma_f32_16x16x32_f16(ah[mi], bl[ni], acc2[mi][ni], 0, 0, 0);
                acc2[mi][ni] = __builtin_amdgcn_mfma_f32_16x16x32_f16(al[mi], bh[ni], acc2[mi][ni], 0, 0, 0);
            }
        __syncthreads();
    }

    const int r0 = (lane >> 4) << 2;
    const long rowBase = (long)bm * 128 + wm * 64;
    const long colBase = (long)bn * 128 + wn * 64;
#pragma unroll
    for (int mi = 0; mi < 4; mi++) {
#pragma unroll
        for (int ni = 0; ni < 4; ni++) {
#pragma unroll
            for (int r = 0; r < 4; r++) {
                long row = rowBase + mi * 16 + r0 + r;
                long col = colBase + ni * 16 + lr;
                float val = acc1[mi][ni][r] + acc2[mi][ni][r] * LINV;
                long ci = (long)z * sC + row * (long)ldc + col;
                if (mode == 2) C[ci] = val + aux[row * (long)auxLd + col];
                else           C[ci] = val;
            }
        }
    }
}

// ---------------------------------------------------------------------------
// bf16 NT GEMM (FFN path). mode 0: f32 store; 3: f32 C += (aux?aux[row*auxLd]:1)*acc.
__global__ __launch_bounds__(256) void gemm_nt_kernel(
    const bf16* __restrict__ A, const bf16* __restrict__ B, void* __restrict__ Cv,
    const float* __restrict__ aux,
    int K, int lda, int ldb, int ldc,
    long sA, long sB, long sC,
    int mode, int auxLd)
{
    __shared__ bf16 As[128 * 40];
    __shared__ bf16 Bs[128 * 40];
    const int tid = threadIdx.x;
    const int bn = blockIdx.x, bm = blockIdx.y, z = blockIdx.z;
    const bf16* Ab = A + (long)z * sA + (long)bm * 128 * lda;
    const bf16* Bb = B + (long)z * sB + (long)bn * 128 * ldb;
    const int lane = tid & 63;
    const int wm = tid >> 7, wn = (tid >> 6) & 1;
    const int lr = lane & 15, lk = (lane >> 4) << 3;
    f32x4 acc[4][4] = {};

    for (int k0 = 0; k0 < K; k0 += 32) {
#pragma unroll
        for (int i = 0; i < 2; i++) {
            int idx = tid + i * 256;
            int rr = idx >> 2, kc = (idx & 3) << 3;
            *(bf16x8*)&As[rr * 40 + kc] = *(const bf16x8*)&Ab[(long)rr * lda + k0 + kc];
            *(bf16x8*)&Bs[rr * 40 + kc] = *(const bf16x8*)&Bb[(long)rr * ldb + k0 + kc];
        }
        __syncthreads();
        bf16x8 af[4], bfr[4];
#pragma unroll
        for (int mi = 0; mi < 4; mi++) af[mi]  = *(const bf16x8*)&As[(wm * 64 + mi * 16 + lr) * 40 + lk];
#pragma unroll
        for (int ni = 0; ni < 4; ni++) bfr[ni] = *(const bf16x8*)&Bs[(wn * 64 + ni * 16 + lr) * 40 + lk];
#pragma unroll
        for (int mi = 0; mi < 4; mi++)
#pragma unroll
            for (int ni = 0; ni < 4; ni++)
                acc[mi][ni] = __builtin_amdgcn_mfma_f32_16x16x32_bf16(af[mi], bfr[ni], acc[mi][ni], 0, 0, 0);
        __syncthreads();
    }

    const int r0 = (lane >> 4) << 2;
    const long rowBase = (long)bm * 128 + wm * 64;
    const long colBase = (long)bn * 128 + wn * 64;
#pragma unroll
    for (int mi = 0; mi < 4; mi++) {
#pragma unroll
        for (int ni = 0; ni < 4; ni++) {
#pragma unroll
            for (int r = 0; r < 4; r++) {
                long row = rowBase + mi * 16 + r0 + r;
                long col = colBase + ni * 16 + lr;
                float val = acc[mi][ni][r];
                long ci = (long)z * sC + row * (long)ldc + col;
                if (mode == 0)      ((float*)Cv)[ci] = val;
                else { float s = aux ? aux[row * auxLd] : 1.f; ((float*)Cv)[ci] += s * val; }
            }
        }
    }
}

// ---------------------------------------------------------------------------
// RMSNorm: f32 in; optional f32 out, bf16 out, f32 raw-copy out.
__global__ __launch_bounds__(256) void rmsnorm_kernel(const float* __restrict__ in,
                                                      const float* __restrict__ w,
                                                      float* __restrict__ outF,
                                                      bf16* __restrict__ outB,
                                                      float* __restrict__ copyOut, int C) {
    long row = blockIdx.x;
    const float* r = in + row * C;
    float ss = 0.f;
    for (int i = threadIdx.x; i < C; i += 256) { float v = r[i]; ss += v * v; }
    for (int off = 32; off > 0; off >>= 1) ss += __shfl_down(ss, off, 64);
    __shared__ float red[5];
    int lane = threadIdx.x & 63, wv = threadIdx.x >> 6;
    if (lane == 0) red[wv] = ss;
    __syncthreads();
    if (threadIdx.x == 0) red[4] = rsqrtf((red[0] + red[1] + red[2] + red[3]) / C + RMS_EPS);
    __syncthreads();
    float sc = red[4];
    for (int i = threadIdx.x; i < C; i += 256) {
        float v = r[i] * sc * w[i];
        if (outF) outF[row * C + i] = v;
        if (outB) outB[row * C + i] = (bf16)v;
        if (copyOut) copyOut[row * C + i] = r[i];
    }
}

// ---------------------------------------------------------------------------
// ckv (T x 640, valid 576) -> kvc = rmsnorm(ckv[:, :512]) f32, krope = rope(ckv[:, 512:576]) f32
__global__ __launch_bounds__(256) void kvsplit_kernel(const float* __restrict__ ckv,
                                                      const float* __restrict__ nrm,
                                                      const float* __restrict__ freq,
                                                      float* __restrict__ kvc,
                                                      float* __restrict__ krope) {
    int t = blockIdx.x; int s = t & (SEQ - 1);
    const float* r = ckv + (long)t * KVDP;
    float ss = 0.f;
    for (int i = threadIdx.x; i < KVCD; i += 256) { float v = r[i]; ss += v * v; }
    for (int off = 32; off > 0; off >>= 1) ss += __shfl_down(ss, off, 64);
    __shared__ float red[5];
    int lane = threadIdx.x & 63, wv = threadIdx.x >> 6;
    if (lane == 0) red[wv] = ss;
    __syncthreads();
    if (threadIdx.x == 0) red[4] = rsqrtf((red[0] + red[1] + red[2] + red[3]) / KVCD + RMS_EPS);
    __syncthreads();
    float sc = red[4];
    for (int i = threadIdx.x; i < KVCD; i += 256) kvc[(long)t * KVCD + i] = r[i] * sc * nrm[i];
    if (threadIdx.x < 32) {
        int i = threadIdx.x;
        float f = freq[s * 32 + i], c = cosf(f), sn = sinf(f);
        float x1 = r[KVCD + 2 * i], x2 = r[KVCD + 2 * i + 1];
        krope[(long)t * ROPED + 2 * i]     = x1 * c - x2 * sn;
        krope[(long)t * ROPED + 2 * i + 1] = x1 * sn + x2 * c;
    }
}

// ---------------------------------------------------------------------------
// q_pre (T x 3072 f32) -> qfull (b*16+h, s, 192) f32, rope on [128,192)
__global__ __launch_bounds__(256) void build_q_kernel(const float* __restrict__ qpre,
                                                      const float* __restrict__ freq,
                                                      float* __restrict__ qfull) {
    int t = blockIdx.x; int b = t >> 10, s = t & (SEQ - 1);
    for (int idx = threadIdx.x; idx < NHEADS * 96; idx += 256) {
        int h = idx / 96, j = idx % 96;
        const float* qrow = qpre + (long)t * 3072 + h * QDIM;
        float* dst = qfull + ((long)(b * NHEADS + h) * SEQ + s) * QDIM;
        if (j < 64) {
            int d = 2 * j;
            dst[d] = qrow[d]; dst[d + 1] = qrow[d + 1];
        } else {
            int i = j - 64;
            float f = freq[s * 32 + i], c = cosf(f), sn = sinf(f);
            float x1 = qrow[NOPED + 2 * i], x2 = qrow[NOPED + 2 * i + 1];
            dst[NOPED + 2 * i]     = x1 * c - x2 * sn;
            dst[NOPED + 2 * i + 1] = x1 * sn + x2 * c;
        }
    }
}

// kv (T x 4096 f32) + krope -> kfull (b*16+h, s, 192) f32, vT (b*16+h, d, s) f32
__global__ __launch_bounds__(256) void build_k_kernel(const float* __restrict__ kv,
                                                      const float* __restrict__ krope,
                                                      float* __restrict__ kfull,
                                                      float* __restrict__ vT) {
    int t = blockIdx.x; int b = t >> 10, s = t & (SEQ - 1);
    const float* kvrow = kv + (long)t * 4096;
    const float* kr = krope + (long)t * ROPED;
    for (int idx = threadIdx.x; idx < NHEADS * 96; idx += 256) {
        int h = idx / 96, j = idx % 96;
        float* dst = kfull + ((long)(b * NHEADS + h) * SEQ + s) * QDIM;
        if (j < 64) {
            int d = 2 * j;
            dst[d] = kvrow[h * 256 + d]; dst[d + 1] = kvrow[h * 256 + d + 1];
        } else {
            int i = j - 64;
            dst[NOPED + 2 * i] = kr[2 * i]; dst[NOPED + 2 * i + 1] = kr[2 * i + 1];
        }
    }
    for (int idx = threadIdx.x; idx < NHEADS * VHD; idx += 256) {
        int h = idx >> 7, d = idx & 127;
        vT[((long)(b * NHEADS + h) * VHD + d) * SEQ + s] = kvrow[h * 256 + NOPED + d];
    }
}

// ---------------------------------------------------------------------------
// softmax in place: row = softmax(row*scale + mask[s,:]) (f32)
__global__ __launch_bounds__(256) void softmax_kernel(float* __restrict__ scores,
                                                      const float* __restrict__ mask,
                                                      float scale) {
    int s = blockIdx.x, h = blockIdx.y;
    float* row  = scores + ((long)h * SEQ + s) * SEQ;
    const float* mrow = mask + (long)s * SEQ;
    float v[4]; float m = -1e30f;
#pragma unroll
    for (int j = 0; j < 4; j++) {
        int i = threadIdx.x + j * 256;
        v[j] = row[i] * scale + mrow[i];
        m = fmaxf(m, v[j]);
    }
    for (int off = 32; off > 0; off >>= 1) m = fmaxf(m, __shfl_down(m, off, 64));
    __shared__ float redm[5], reds[5];
    int lane = threadIdx.x & 63, wv = threadIdx.x >> 6;
    if (lane == 0) redm[wv] = m;
    __syncthreads();
    if (threadIdx.x == 0) redm[4] = fmaxf(fmaxf(redm[0], redm[1]), fmaxf(redm[2], redm[3]));
    __syncthreads();
    float M = redm[4];
    float sum = 0.f;
#pragma unroll
    for (int j = 0; j < 4; j++) { v[j] = expf(v[j] - M); sum += v[j]; }
    for (int off = 32; off > 0; off >>= 1) sum += __shfl_down(sum, off, 64);
    if (lane == 0) reds[wv] = sum;
    __syncthreads();
    if (threadIdx.x == 0) reds[4] = reds[0] + reds[1] + reds[2] + reds[3];
    __syncthreads();
    float inv = 1.f / reds[4];
#pragma unroll
    for (int j = 0; j < 4; j++) row[threadIdx.x + j * 256] = v[j] * inv;
}

// ---------------------------------------------------------------------------
// router (f32): t = rmsnorm(x2)*w_ffn; logits = t@W_r; softmax; top2 -> wts (T x 8)
__global__ __launch_bounds__(64) void router_kernel(const float* __restrict__ x2,
                                                    const float* __restrict__ wffn,
                                                    const float* __restrict__ Wr,
                                                    float* __restrict__ wts) {
    int t = blockIdx.x; int lane = threadIdx.x;
    const float* r = x2 + (long)t * HIDD;
    float ss = 0.f;
    for (int k = lane; k < HIDD; k += 64) { float v = r[k]; ss += v * v; }
    for (int off = 32; off > 0; off >>= 1) ss += __shfl_down(ss, off, 64);
    float sc = rsqrtf(__shfl(ss, 0, 64) / HIDD + RMS_EPS);
    float acc[8] = {0, 0, 0, 0, 0, 0, 0, 0};
    for (int k = lane; k < HIDD; k += 64) {
        float tv = r[k] * sc * wffn[k];
        const float* wr = Wr + (long)k * 8;
#pragma unroll
        for (int e = 0; e < 8; e++) acc[e] += tv * wr[e];
    }
#pragma unroll
    for (int e = 0; e < 8; e++)
        for (int off = 32; off > 0; off >>= 1) acc[e] += __shfl_down(acc[e], off, 64);
    if (lane == 0) {
        float m = acc[0];
#pragma unroll
        for (int e = 1; e < 8; e++) m = fmaxf(m, acc[e]);
        float p[8]; float se = 0.f;
#pragma unroll
        for (int e = 0; e < 8; e++) { p[e] = expf(acc[e] - m); se += p[e]; }
        float inv = 1.f / se;
        int i1 = 0; float v1 = p[0];
        for (int e = 1; e < 8; e++) if (p[e] > v1) { v1 = p[e]; i1 = e; }
        int i2 = -1; float v2 = -1.f;
        for (int e = 0; e < 8; e++) if (e != i1 && p[e] > v2) { v2 = p[e]; i2 = e; }
#pragma unroll
        for (int e = 0; e < 8; e++)
            wts[(long)t * 8 + e] = (e == i1) ? v1 * inv : ((e == i2) ? v2 * inv : 0.f);
    }
}

// hid = silu(gu[:, :1408]) * gu[:, 1408:]
__global__ __launch_bounds__(256) void silumul_kernel(const float* __restrict__ gu,
                                                      bf16* __restrict__ hid) {
    long t = blockIdx.x;
    const float* row = gu + t * GUD;
    bf16* h = hid + t * INTERD;
    for (int i = threadIdx.x; i < INTERD; i += 256) {
        float g = row[i], u = row[INTERD + i];
        h[i] = (bf16)(g / (1.f + expf(-g)) * u);
    }
}

// ---------------------------------------------------------------------------
static inline size_t alignup(size_t v) { return (v + 255) & ~(size_t)255; }

extern "C" void kernel_launch(void* const* d_in, const int* in_sizes, int n_in,
                              void* d_out, int out_size, void* d_ws, size_t ws_size,
                              hipStream_t stream) {
    const float* x       = (const float*)d_in[0];
    const float* freq    = (const float*)d_in[1];
    const float* mask    = (const float*)d_in[2];
    const float* w_attn  = (const float*)d_in[3];
    const float* w_ffn   = (const float*)d_in[4];
    const float* W_dq    = (const float*)d_in[5];
    const float* q_c_nrm = (const float*)d_in[6];
    const float* W_uq    = (const float*)d_in[7];
    const float* W_dkv   = (const float*)d_in[8];
    const float* kv_nrm  = (const float*)d_in[9];
    const float* W_ukv   = (const float*)d_in[10];
    const float* W_o     = (const float*)d_in[11];
    const float* W_r     = (const float*)d_in[12];
    const float* Ws_gate = (const float*)d_in[13];
    const float* Ws_up   = (const float*)d_in[14];
    const float* Ws_down = (const float*)d_in[15];
    const float* We_gate = (const float*)d_in[16];
    const float* We_up   = (const float*)d_in[17];
    const float* We_down = (const float*)d_in[18];
    float* out = (float*)d_out;
    char* ws = (char*)d_ws;
    (void)in_sizes; (void)n_in; (void)out_size;

    // ---- workspace layout (total ~240 MB) ----
    size_t o = 0;
    auto alloc = [&](size_t n) { size_t r = o; o += alignup(n); return r; };
    size_t oWslot = alloc((size_t)3072 * QCD * 4);           // 18.9 MB rotating weight slot
    size_t oQfull = alloc((size_t)32 * SEQ * QDIM * 4);      // 25.2
    size_t oKfull = alloc((size_t)32 * SEQ * QDIM * 4);      // 25.2
    size_t oVT    = alloc((size_t)32 * VHD * SEQ * 4);       // 16.8
    size_t oAttn  = alloc((size_t)TOK * HIDD * 4);           // 16.8
    size_t oX2    = alloc((size_t)TOK * HIDD * 4);           // 16.8
    size_t oTbuf  = alloc((size_t)TOK * HIDD * 2);           // 8.4
    size_t oWts   = alloc((size_t)TOK * 8 * 4);
    size_t oKrope = alloc((size_t)TOK * ROPED * 4);          // 0.5
    // overlay arena: early chain | scores | gu+hid
    size_t zH    = alignup((size_t)TOK * HIDD * 4);          // 16.8
    size_t zCqp  = alignup((size_t)TOK * QCD * 4);           // 12.6
    size_t zCq   = alignup((size_t)TOK * QCD * 4);           // 12.6
    size_t zQp   = alignup((size_t)TOK * 3072 * 4);          // 25.2
    size_t zCkv  = alignup((size_t)TOK * KVDP * 4);          // 5.2
    size_t zKvc  = alignup((size_t)TOK * KVCD * 4);          // 4.2
    size_t zKv   = alignup((size_t)TOK * 4096 * 4);          // 33.6
    size_t chain = zH + zCqp + zCq + zQp + zCkv + zKvc + zKv; // 110.2
    size_t zScores = alignup((size_t)8 * SEQ * SEQ * 4);      // 33.6 (8-head chunk, in-place P)
    size_t zGu     = alignup((size_t)TOK * GUD * 4);          // 23.1
    size_t zHid    = alignup((size_t)TOK * INTERD * 2);       // 5.8
    size_t arenaSz = chain;
    if (zScores > arenaSz) arenaSz = zScores;
    if (zGu + zHid > arenaSz) arenaSz = zGu + zHid;
    size_t oArena = alloc(arenaSz);
    if (ws_size < o) return;

    size_t oH    = oArena;
    size_t oCqp  = oH + zH;
    size_t oCq   = oCqp + zCqp;
    size_t oQp   = oCq + zCq;
    size_t oCkv  = oQp + zQp;
    size_t oKvc  = oCkv + zCkv;
    size_t oKv   = oKvc + zKvc;
    size_t oScores = oArena;
    size_t oGu     = oArena;
    size_t oHid    = oArena + zGu;

    float* wslotF = (float*)(ws + oWslot);
    bf16*  wslotB = (bf16*)(ws + oWslot);                          // GU bf16 (11.5 MB)
    bf16*  wslotB2 = (bf16*)(ws + oWslot + (size_t)GUD * HIDD * 2); // down bf16 (5.8 MB)
    float* qfull = (float*)(ws + oQfull);
    float* kfull = (float*)(ws + oKfull);
    float* vT    = (float*)(ws + oVT);
    float* attn  = (float*)(ws + oAttn);
    float* x2    = (float*)(ws + oX2);
    bf16*  tbuf  = (bf16*)(ws + oTbuf);
    float* wts   = (float*)(ws + oWts);
    float* krope = (float*)(ws + oKrope);
    float* h     = (float*)(ws + oH);
    float* cqpre = (float*)(ws + oCqp);
    float* cq    = (float*)(ws + oCq);
    float* qpre  = (float*)(ws + oQp);
    float* ckv   = (float*)(ws + oCkv);
    float* kvc   = (float*)(ws + oKvc);
    float* kv    = (float*)(ws + oKv);
    float* scores = (float*)(ws + oScores);
    float* gu    = (float*)(ws + oGu);
    bf16*  hid   = (bf16*)(ws + oHid);

    auto tconvf = [&](const float* src, float* dst, int K, int N, int Npad) {
        dim3 g((Npad + 31) / 32, (K + 31) / 32);
        tconvf_kernel<<<g, 256, 0, stream>>>(src, dst, K, N, Npad);
    };
    auto tconv = [&](const float* src, bf16* dst, int K, int N, int Npad) {
        dim3 g((Npad + 31) / 32, (K + 31) / 32);
        tconv_kernel<<<g, 256, 0, stream>>>(src, dst, K, N, Npad);
    };
    auto gemmS = [&](const float* A, const float* B, float* C, const float* aux,
                     int M, int N, int K, int lda, int ldb, int ldc,
                     long sA, long sB, long sC, int Z, int mode, int auxLd) {
        dim3 g(N / 128, M / 128, Z);
        gemm_f32s_kernel<<<g, 256, 0, stream>>>(A, B, C, aux, K, lda, ldb, ldc, sA, sB, sC, mode, auxLd);
    };
    auto gemmB = [&](const bf16* A, const bf16* B, void* C, const float* aux,
                     int M, int N, int K, int lda, int ldb, int ldc, int mode, int auxLd) {
        dim3 g(N / 128, M / 128, 1);
        gemm_nt_kernel<<<g, 256, 0, stream>>>(A, B, C, aux, K, lda, ldb, ldc, 0, 0, 0, mode, auxLd);
    };

    // ---- attention pipeline (f32 activations, split-fp16 GEMMs) ----
    rmsnorm_kernel<<<TOK, 256, 0, stream>>>(x, w_attn, h, nullptr, nullptr, HIDD);

    tconvf(W_dq, wslotF, HIDD, QCD, QCD);
    gemmS(h, wslotF, cqpre, nullptr, TOK, QCD, HIDD, HIDD, HIDD, QCD, 0, 0, 0, 1, 0, 0);
    rmsnorm_kernel<<<TOK, 256, 0, stream>>>(cqpre, q_c_nrm, cq, nullptr, nullptr, QCD);

    tconvf(W_uq, wslotF, QCD, 3072, 3072);
    gemmS(cq, wslotF, qpre, nullptr, TOK, 3072, QCD, QCD, QCD, 3072, 0, 0, 0, 1, 0, 0);

    tconvf(W_dkv, wslotF, HIDD, KVD, KVDP);
    gemmS(h, wslotF, ckv, nullptr, TOK, KVDP, HIDD, HIDD, HIDD, KVDP, 0, 0, 0, 1, 0, 0);
    kvsplit_kernel<<<TOK, 256, 0, stream>>>(ckv, kv_nrm, freq, kvc, krope);

    tconvf(W_ukv, wslotF, KVCD, 4096, 4096);
    gemmS(kvc, wslotF, kv, nullptr, TOK, 4096, KVCD, KVCD, KVCD, 4096, 0, 0, 0, 1, 0, 0);

    build_q_kernel<<<TOK, 256, 0, stream>>>(qpre, freq, qfull);
    build_k_kernel<<<TOK, 256, 0, stream>>>(kv, krope, kfull, vT);

    const float scale = 1.f / sqrtf((float)QDIM);
    for (int b = 0; b < 2; b++) {
        for (int hc = 0; hc < 2; hc++) {
            int h0 = b * NHEADS + hc * 8;
            gemmS(qfull + (size_t)h0 * SEQ * QDIM, kfull + (size_t)h0 * SEQ * QDIM,
                  scores, nullptr, SEQ, SEQ, QDIM, QDIM, QDIM, SEQ,
                  (long)SEQ * QDIM, (long)SEQ * QDIM, (long)SEQ * SEQ, 8, 0, 0);
            softmax_kernel<<<dim3(SEQ, 8), 256, 0, stream>>>(scores, mask, scale);
            gemmS(scores, vT + (size_t)h0 * VHD * SEQ,
                  attn + (size_t)b * SEQ * HIDD + (size_t)(hc * 8) * VHD, nullptr,
                  SEQ, VHD, SEQ, SEQ, SEQ, HIDD,
                  (long)SEQ * SEQ, (long)VHD * SEQ, (long)VHD, 8, 0, 0);
        }
    }

    tconvf(W_o, wslotF, HIDD, HIDD, HIDD);
    gemmS(attn, wslotF, x2, x, TOK, HIDD, HIDD, HIDD, HIDD, HIDD, 0, 0, 0, 1, 2, HIDD);

    // ---- MoE ----
    rmsnorm_kernel<<<TOK, 256, 0, stream>>>(x2, w_ffn, nullptr, tbuf, out, HIDD); // out = x2
    router_kernel<<<TOK, 64, 0, stream>>>(x2, w_ffn, W_r, wts);

    for (int e = 0; e < 2; e++) {
        tconv(Ws_gate + (size_t)e * HIDD * INTERD, wslotB, HIDD, INTERD, INTERD);
        tconv(Ws_up   + (size_t)e * HIDD * INTERD, wslotB + (size_t)INTERD * HIDD, HIDD, INTERD, INTERD);
        gemmB(tbuf, wslotB, gu, nullptr, TOK, GUD, HIDD, HIDD, HIDD, GUD, 0, 0);
        silumul_kernel<<<TOK, 256, 0, stream>>>(gu, hid);
        tconv(Ws_down + (size_t)e * INTERD * HIDD, wslotB2, INTERD, HIDD, HIDD);
        gemmB(hid, wslotB2, out, nullptr, TOK, HIDD, INTERD, INTERD, INTERD, HIDD, 3, 0);
    }
    for (int e = 0; e < 8; e++) {
        tconv(We_gate + (size_t)e * HIDD * INTERD, wslotB, HIDD, INTERD, INTERD);
        tconv(We_up   + (size_t)e * HIDD * INTERD, wslotB + (size_t)INTERD * HIDD, HIDD, INTERD, INTERD);
        gemmB(tbuf, wslotB, gu, nullptr, TOK, GUD, HIDD, HIDD, HIDD, GUD, 0, 0);
        silumul_kernel<<<TOK, 256, 0, stream>>>(gu, hid);
        tconv(We_down + (size_t)e * INTERD * HIDD, wslotB2, INTERD, HIDD, HIDD);
        gemmB(hid, wslotB2, out, wts + e, TOK, HIDD, INTERD, INTERD, INTERD, HIDD, 3, 8);
    }
}

// Round 4
// 2441.183 us; speedup vs baseline: 1.0180x; 1.0180x over previous
//
#include <hip/hip_runtime.h>

typedef __bf16 bf16;
typedef __bf16 bf16x8 __attribute__((ext_vector_type(8)));
typedef _Float16 f16;
typedef _Float16 f16x8 __attribute__((ext_vector_type(8)));
typedef _Float16 f16x4 __attribute__((ext_vector_type(4)));
typedef float f32x4 __attribute__((ext_vector_type(4)));

#define TOK   2048   // B*S
#define SEQ   1024
#define HIDD  2048
#define NHEADS 16
#define QCD   1536
#define KVCD  512
#define ROPED 64
#define NOPED 128
#define QDIM  192    // NOPE+ROPE
#define VHD   128
#define KVD   576
#define KVDP  640    // padded to multiple of 128
#define INTERD 1408
#define GUD   2816   // 2*INTER (gate|up fused)
#define RMS_EPS 1e-6f
#define LSCALE 2048.0f
#define LINV   (1.0f/2048.0f)

// ---------------------------------------------------------------------------
__device__ inline void gl_lds16(const void* g, void* l) {
    __builtin_amdgcn_global_load_lds(
        (const __attribute__((address_space(1))) void*)g,
        (__attribute__((address_space(3))) void*)l,
        16, 0, 0);
}

// ---------------------------------------------------------------------------
// Transpose-convert f32: src (K,N) f32 -> dst (Npad,K) f32. Rows [N,Npad) zero.
__global__ __launch_bounds__(256) void tconvf_kernel(const float* __restrict__ src,
                                                     float* __restrict__ dst,
                                                     int K, int N, int Npad) {
    __shared__ float tile[32][33];
    int nb = blockIdx.x * 32, kb = blockIdx.y * 32;
    int tx = threadIdx.x & 31, ty = threadIdx.x >> 5;
#pragma unroll
    for (int i = 0; i < 32; i += 8) {
        int k = kb + ty + i, n = nb + tx;
        tile[ty + i][tx] = (k < K && n < N) ? src[(long)k * N + n] : 0.f;
    }
    __syncthreads();
#pragma unroll
    for (int i = 0; i < 32; i += 8) {
        int n = nb + ty + i, k = kb + tx;
        if (n < Npad && k < K) dst[(long)n * K + k] = tile[tx][ty + i];
    }
}

// Transpose-convert bf16: src (K,N) f32 -> dst (Npad,K) bf16.
__global__ __launch_bounds__(256) void tconv_kernel(const float* __restrict__ src,
                                                    bf16* __restrict__ dst,
                                                    int K, int N, int Npad) {
    __shared__ float tile[32][33];
    int nb = blockIdx.x * 32, kb = blockIdx.y * 32;
    int tx = threadIdx.x & 31, ty = threadIdx.x >> 5;
#pragma unroll
    for (int i = 0; i < 32; i += 8) {
        int k = kb + ty + i, n = nb + tx;
        tile[ty + i][tx] = (k < K && n < N) ? src[(long)k * N + n] : 0.f;
    }
    __syncthreads();
#pragma unroll
    for (int i = 0; i < 32; i += 8) {
        int n = nb + ty + i, k = kb + tx;
        if (n < Npad && k < K) dst[(long)n * K + k] = (bf16)tile[tx][ty + i];
    }
}

// ---------------------------------------------------------------------------
// Split-precision NT GEMM (attention path): C = A*B^T, A,B f32, fp16 hi/lo split
// staged in LDS, 3 MFMA passes. mode 0: f32 store; 2: f32 store + aux (residual).
__global__ __launch_bounds__(256) void gemm_f32s_kernel(
    const float* __restrict__ A, const float* __restrict__ B, float* __restrict__ C,
    const float* __restrict__ aux,
    int K, int lda, int ldb, int ldc,
    long sA, long sB, long sC,
    int mode, int auxLd)
{
    __shared__ f16 AhS[128 * 40], AlS[128 * 40], BhS[128 * 40], BlS[128 * 40];
    const int tid = threadIdx.x;
    const int bn = blockIdx.x, bm = blockIdx.y, z = blockIdx.z;
    const float* Ab = A + (long)z * sA + (long)bm * 128 * lda;
    const float* Bb = B + (long)z * sB + (long)bn * 128 * ldb;
    const int lane = tid & 63;
    const int wm = tid >> 7, wn = (tid >> 6) & 1;
    const int lr = lane & 15, lk = (lane >> 4) << 3;
    f32x4 acc1[4][4] = {};
    f32x4 acc2[4][4] = {};

    for (int k0 = 0; k0 < K; k0 += 32) {
#pragma unroll
        for (int i = 0; i < 4; i++) {
            int idx = tid + i * 256;
            int rr = idx >> 3, kc = (idx & 7) << 2;
            f32x4 va = *(const f32x4*)&Ab[(long)rr * lda + k0 + kc];
            f32x4 vb = *(const f32x4*)&Bb[(long)rr * ldb + k0 + kc];
            f16x4 ha, la, hb, lb;
#pragma unroll
            for (int j = 0; j < 4; j++) {
                f16 h = (f16)va[j]; ha[j] = h; la[j] = (f16)((va[j] - (float)h) * LSCALE);
                f16 g = (f16)vb[j]; hb[j] = g; lb[j] = (f16)((vb[j] - (float)g) * LSCALE);
            }
            *(f16x4*)&AhS[rr * 40 + kc] = ha; *(f16x4*)&AlS[rr * 40 + kc] = la;
            *(f16x4*)&BhS[rr * 40 + kc] = hb; *(f16x4*)&BlS[rr * 40 + kc] = lb;
        }
        __syncthreads();
        f16x8 ah[4], al[4], bh[4], bl[4];
#pragma unroll
        for (int mi = 0; mi < 4; mi++) {
            int r = (wm * 64 + mi * 16 + lr) * 40 + lk;
            ah[mi] = *(const f16x8*)&AhS[r]; al[mi] = *(const f16x8*)&AlS[r];
        }
#pragma unroll
        for (int ni = 0; ni < 4; ni++) {
            int r = (wn * 64 + ni * 16 + lr) * 40 + lk;
            bh[ni] = *(const f16x8*)&BhS[r]; bl[ni] = *(const f16x8*)&BlS[r];
        }
#pragma unroll
        for (int mi = 0; mi < 4; mi++)
#pragma unroll
            for (int ni = 0; ni < 4; ni++) {
                acc1[mi][ni] = __builtin_amdgcn_mfma_f32_16x16x32_f16(ah[mi], bh[ni], acc1[mi][ni], 0, 0, 0);
                acc2[mi][ni] = __builtin_amdgcn_mfma_f32_16x16x32_f16(ah[mi], bl[ni], acc2[mi][ni], 0, 0, 0);
                acc2[mi][ni] = __builtin_amdgcn_mfma_f32_16x16x32_f16(al[mi], bh[ni], acc2[mi][ni], 0, 0, 0);
            }
        __syncthreads();
    }

    const int r0 = (lane >> 4) << 2;
    const long rowBase = (long)bm * 128 + wm * 64;
    const long colBase = (long)bn * 128 + wn * 64;
#pragma unroll
    for (int mi = 0; mi < 4; mi++) {
#pragma unroll
        for (int ni = 0; ni < 4; ni++) {
#pragma unroll
            for (int r = 0; r < 4; r++) {
                long row = rowBase + mi * 16 + r0 + r;
                long col = colBase + ni * 16 + lr;
                float val = acc1[mi][ni][r] + acc2[mi][ni][r] * LINV;
                long ci = (long)z * sC + row * (long)ldc + col;
                if (mode == 2) C[ci] = val + aux[row * (long)auxLd + col];
                else           C[ci] = val;
            }
        }
    }
}

// ---------------------------------------------------------------------------
// Fast bf16 NT GEMM (m97 structure): 128x128 tile, BK=64, global_load_lds x16.
// mode 0: f32 store; 3: f32 C += (aux?aux[row*auxLd]:1)*acc;
// mode 5: scatter  out[idx[row]*ldc+col] += aux[idx[row]*auxLd]*val for row<cnt.
// cntPtr (optional): device count; blocks with bm*128 >= padded count exit.
__global__ __launch_bounds__(256) void gemm_bt_kernel(
    const bf16* __restrict__ A, const bf16* __restrict__ B, void* __restrict__ Cv,
    const float* __restrict__ aux, const int* __restrict__ idx,
    const int* __restrict__ cntPtr,
    int K, int lda, int ldb, int ldc, int mode, int auxLd)
{
    __shared__ bf16 As[128 * 64];
    __shared__ bf16 Bs[128 * 64];
    const int bn = blockIdx.x, bm = blockIdx.y;
    int cnt = 1 << 30;
    if (cntPtr) {
        cnt = *cntPtr;
        int pad = (cnt + 127) & ~127;
        if (bm * 128 >= pad) return;
    }
    const int tid = threadIdx.x;
    const int lane = tid & 63;
    const int w = tid >> 6;                 // wave 0..3
    const int wm = w >> 1, wn = w & 1;
    const int lr = lane & 15, lk = (lane >> 4) << 3;
    const int srow = lane >> 3;             // 0..7
    const int scol = (lane & 7) << 3;       // elem col, 16B granules
    const bf16* Ab = A + (long)bm * 128 * lda;
    const bf16* Bb = B + (long)bn * 128 * ldb;
    f32x4 acc[4][4] = {};

    for (int k0 = 0; k0 < K; k0 += 64) {
#pragma unroll
        for (int i = 0; i < 4; i++) {
            int r = i * 32 + w * 8;         // wave-uniform row base (8 rows/instr)
            gl_lds16(&Ab[(long)(r + srow) * lda + k0 + scol], &As[r * 64]);
            gl_lds16(&Bb[(long)(r + srow) * ldb + k0 + scol], &Bs[r * 64]);
        }
        __syncthreads();
#pragma unroll
        for (int ks = 0; ks < 2; ks++) {
            bf16x8 af[4], bfr[4];
#pragma unroll
            for (int mi = 0; mi < 4; mi++)
                af[mi] = *(const bf16x8*)&As[(wm * 64 + mi * 16 + lr) * 64 + ks * 32 + lk];
#pragma unroll
            for (int ni = 0; ni < 4; ni++)
                bfr[ni] = *(const bf16x8*)&Bs[(wn * 64 + ni * 16 + lr) * 64 + ks * 32 + lk];
#pragma unroll
            for (int mi = 0; mi < 4; mi++)
#pragma unroll
                for (int ni = 0; ni < 4; ni++)
                    acc[mi][ni] = __builtin_amdgcn_mfma_f32_16x16x32_bf16(af[mi], bfr[ni], acc[mi][ni], 0, 0, 0);
        }
        __syncthreads();
    }

    const int r0 = (lane >> 4) << 2;
    const int rowBase = bm * 128 + wm * 64;
    const int colBase = bn * 128 + wn * 64;
#pragma unroll
    for (int mi = 0; mi < 4; mi++) {
#pragma unroll
        for (int ni = 0; ni < 4; ni++) {
#pragma unroll
            for (int r = 0; r < 4; r++) {
                int row = rowBase + mi * 16 + r0 + r;
                int col = colBase + ni * 16 + lr;
                float val = acc[mi][ni][r];
                if (mode == 0) {
                    ((float*)Cv)[(long)row * ldc + col] = val;
                } else if (mode == 3) {
                    float s = aux ? aux[(long)row * auxLd] : 1.f;
                    ((float*)Cv)[(long)row * ldc + col] += s * val;
                } else {
                    if (row < cnt) {
                        int tok = idx[row];
                        ((float*)Cv)[(long)tok * ldc + col] += aux[(long)tok * auxLd] * val;
                    }
                }
            }
        }
    }
}

// ---------------------------------------------------------------------------
// RMSNorm: f32 in; optional f32 out, bf16 out, f32 raw-copy out.
__global__ __launch_bounds__(256) void rmsnorm_kernel(const float* __restrict__ in,
                                                      const float* __restrict__ w,
                                                      float* __restrict__ outF,
                                                      bf16* __restrict__ outB,
                                                      float* __restrict__ copyOut, int C) {
    long row = blockIdx.x;
    const float* r = in + row * C;
    float ss = 0.f;
    for (int i = threadIdx.x; i < C; i += 256) { float v = r[i]; ss += v * v; }
    for (int off = 32; off > 0; off >>= 1) ss += __shfl_down(ss, off, 64);
    __shared__ float red[5];
    int lane = threadIdx.x & 63, wv = threadIdx.x >> 6;
    if (lane == 0) red[wv] = ss;
    __syncthreads();
    if (threadIdx.x == 0) red[4] = rsqrtf((red[0] + red[1] + red[2] + red[3]) / C + RMS_EPS);
    __syncthreads();
    float sc = red[4];
    for (int i = threadIdx.x; i < C; i += 256) {
        float v = r[i] * sc * w[i];
        if (outF) outF[row * C + i] = v;
        if (outB) outB[row * C + i] = (bf16)v;
        if (copyOut) copyOut[row * C + i] = r[i];
    }
}

// ---------------------------------------------------------------------------
// ckv (T x 640, valid 576) -> kvc = rmsnorm(ckv[:, :512]) f32, krope = rope f32
__global__ __launch_bounds__(256) void kvsplit_kernel(const float* __restrict__ ckv,
                                                      const float* __restrict__ nrm,
                                                      const float* __restrict__ freq,
                                                      float* __restrict__ kvc,
                                                      float* __restrict__ krope) {
    int t = blockIdx.x; int s = t & (SEQ - 1);
    const float* r = ckv + (long)t * KVDP;
    float ss = 0.f;
    for (int i = threadIdx.x; i < KVCD; i += 256) { float v = r[i]; ss += v * v; }
    for (int off = 32; off > 0; off >>= 1) ss += __shfl_down(ss, off, 64);
    __shared__ float red[5];
    int lane = threadIdx.x & 63, wv = threadIdx.x >> 6;
    if (lane == 0) red[wv] = ss;
    __syncthreads();
    if (threadIdx.x == 0) red[4] = rsqrtf((red[0] + red[1] + red[2] + red[3]) / KVCD + RMS_EPS);
    __syncthreads();
    float sc = red[4];
    for (int i = threadIdx.x; i < KVCD; i += 256) kvc[(long)t * KVCD + i] = r[i] * sc * nrm[i];
    if (threadIdx.x < 32) {
        int i = threadIdx.x;
        float f = freq[s * 32 + i], c = cosf(f), sn = sinf(f);
        float x1 = r[KVCD + 2 * i], x2 = r[KVCD + 2 * i + 1];
        krope[(long)t * ROPED + 2 * i]     = x1 * c - x2 * sn;
        krope[(long)t * ROPED + 2 * i + 1] = x1 * sn + x2 * c;
    }
}

// ---------------------------------------------------------------------------
// q_pre (T x 3072 f32) -> qfull (b*16+h, s, 192) f32, rope on [128,192)
__global__ __launch_bounds__(256) void build_q_kernel(const float* __restrict__ qpre,
                                                      const float* __restrict__ freq,
                                                      float* __restrict__ qfull) {
    int t = blockIdx.x; int b = t >> 10, s = t & (SEQ - 1);
    for (int idx = threadIdx.x; idx < NHEADS * 96; idx += 256) {
        int h = idx / 96, j = idx % 96;
        const float* qrow = qpre + (long)t * 3072 + h * QDIM;
        float* dst = qfull + ((long)(b * NHEADS + h) * SEQ + s) * QDIM;
        if (j < 64) {
            int d = 2 * j;
            dst[d] = qrow[d]; dst[d + 1] = qrow[d + 1];
        } else {
            int i = j - 64;
            float f = freq[s * 32 + i], c = cosf(f), sn = sinf(f);
            float x1 = qrow[NOPED + 2 * i], x2 = qrow[NOPED + 2 * i + 1];
            dst[NOPED + 2 * i]     = x1 * c - x2 * sn;
            dst[NOPED + 2 * i + 1] = x1 * sn + x2 * c;
        }
    }
}

// kv (T x 4096 f32) + krope -> kfull (b*16+h, s, 192) f32, vT (b*16+h, d, s) f32
__global__ __launch_bounds__(256) void build_k_kernel(const float* __restrict__ kv,
                                                      const float* __restrict__ krope,
                                                      float* __restrict__ kfull,
                                                      float* __restrict__ vT) {
    int t = blockIdx.x; int b = t >> 10, s = t & (SEQ - 1);
    const float* kvrow = kv + (long)t * 4096;
    const float* kr = krope + (long)t * ROPED;
    for (int idx = threadIdx.x; idx < NHEADS * 96; idx += 256) {
        int h = idx / 96, j = idx % 96;
        float* dst = kfull + ((long)(b * NHEADS + h) * SEQ + s) * QDIM;
        if (j < 64) {
            int d = 2 * j;
            dst[d] = kvrow[h * 256 + d]; dst[d + 1] = kvrow[h * 256 + d + 1];
        } else {
            int i = j - 64;
            dst[NOPED + 2 * i] = kr[2 * i]; dst[NOPED + 2 * i + 1] = kr[2 * i + 1];
        }
    }
    for (int idx = threadIdx.x; idx < NHEADS * VHD; idx += 256) {
        int h = idx >> 7, d = idx & 127;
        vT[((long)(b * NHEADS + h) * VHD + d) * SEQ + s] = kvrow[h * 256 + NOPED + d];
    }
}

// ---------------------------------------------------------------------------
// softmax in place: row = softmax(row*scale + mask[s,:]) (f32)
__global__ __launch_bounds__(256) void softmax_kernel(float* __restrict__ scores,
                                                      const float* __restrict__ mask,
                                                      float scale) {
    int s = blockIdx.x, h = blockIdx.y;
    float* row  = scores + ((long)h * SEQ + s) * SEQ;
    const float* mrow = mask + (long)s * SEQ;
    float v[4]; float m = -1e30f;
#pragma unroll
    for (int j = 0; j < 4; j++) {
        int i = threadIdx.x + j * 256;
        v[j] = row[i] * scale + mrow[i];
        m = fmaxf(m, v[j]);
    }
    for (int off = 32; off > 0; off >>= 1) m = fmaxf(m, __shfl_down(m, off, 64));
    __shared__ float redm[5], reds[5];
    int lane = threadIdx.x & 63, wv = threadIdx.x >> 6;
    if (lane == 0) redm[wv] = m;
    __syncthreads();
    if (threadIdx.x == 0) redm[4] = fmaxf(fmaxf(redm[0], redm[1]), fmaxf(redm[2], redm[3]));
    __syncthreads();
    float M = redm[4];
    float sum = 0.f;
#pragma unroll
    for (int j = 0; j < 4; j++) { v[j] = expf(v[j] - M); sum += v[j]; }
    for (int off = 32; off > 0; off >>= 1) sum += __shfl_down(sum, off, 64);
    if (lane == 0) reds[wv] = sum;
    __syncthreads();
    if (threadIdx.x == 0) reds[4] = reds[0] + reds[1] + reds[2] + reds[3];
    __syncthreads();
    float inv = 1.f / reds[4];
#pragma unroll
    for (int j = 0; j < 4; j++) row[threadIdx.x + j * 256] = v[j] * inv;
}

// ---------------------------------------------------------------------------
__global__ void zero_counts_kernel(int* counts) {
    if (threadIdx.x < 8) counts[threadIdx.x] = 0;
}

// router (f32): t = rmsnorm(x2)*w_ffn; logits = t@W_r; softmax; top2 -> wts,
// plus per-expert compact token lists (perm, counts).
__global__ __launch_bounds__(64) void router_kernel(const float* __restrict__ x2,
                                                    const float* __restrict__ wffn,
                                                    const float* __restrict__ Wr,
                                                    float* __restrict__ wts,
                                                    int* __restrict__ perm,
                                                    int* __restrict__ counts) {
    int t = blockIdx.x; int lane = threadIdx.x;
    const float* r = x2 + (long)t * HIDD;
    float ss = 0.f;
    for (int k = lane; k < HIDD; k += 64) { float v = r[k]; ss += v * v; }
    for (int off = 32; off > 0; off >>= 1) ss += __shfl_down(ss, off, 64);
    float sc = rsqrtf(__shfl(ss, 0, 64) / HIDD + RMS_EPS);
    float acc[8] = {0, 0, 0, 0, 0, 0, 0, 0};
    for (int k = lane; k < HIDD; k += 64) {
        float tv = r[k] * sc * wffn[k];
        const float* wr = Wr + (long)k * 8;
#pragma unroll
        for (int e = 0; e < 8; e++) acc[e] += tv * wr[e];
    }
#pragma unroll
    for (int e = 0; e < 8; e++)
        for (int off = 32; off > 0; off >>= 1) acc[e] += __shfl_down(acc[e], off, 64);
    if (lane == 0) {
        float m = acc[0];
#pragma unroll
        for (int e = 1; e < 8; e++) m = fmaxf(m, acc[e]);
        float p[8]; float se = 0.f;
#pragma unroll
        for (int e = 0; e < 8; e++) { p[e] = expf(acc[e] - m); se += p[e]; }
        float inv = 1.f / se;
        int i1 = 0; float v1 = p[0];
        for (int e = 1; e < 8; e++) if (p[e] > v1) { v1 = p[e]; i1 = e; }
        int i2 = -1; float v2 = -1.f;
        for (int e = 0; e < 8; e++) if (e != i1 && p[e] > v2) { v2 = p[e]; i2 = e; }
#pragma unroll
        for (int e = 0; e < 8; e++)
            wts[(long)t * 8 + e] = (e == i1) ? v1 * inv : ((e == i2) ? v2 * inv : 0.f);
        int s1 = atomicAdd(&counts[i1], 1); perm[i1 * TOK + s1] = t;
        int s2 = atomicAdd(&counts[i2], 1); perm[i2 * TOK + s2] = t;
    }
}

// gather: tA[row] = tbuf[perm[row]] for row<cnt; zeros for row in [cnt,pad).
__global__ __launch_bounds__(256) void gather_kernel(const bf16* __restrict__ tbuf,
                                                     const int* __restrict__ perm,
                                                     const int* __restrict__ cntPtr,
                                                     bf16* __restrict__ tA) {
    int row = blockIdx.x;
    int cnt = *cntPtr;
    int pad = (cnt + 127) & ~127;
    if (row >= pad) return;
    int i = threadIdx.x * 8;  // 256*8 = 2048 = HIDD
    if (row < cnt) {
        int tok = perm[row];
        *(bf16x8*)&tA[(long)row * HIDD + i] = *(const bf16x8*)&tbuf[(long)tok * HIDD + i];
    } else {
        bf16x8 z = {};
        *(bf16x8*)&tA[(long)row * HIDD + i] = z;
    }
}

// hid = silu(gu[:, :1408]) * gu[:, 1408:]; optional count-based early exit
__global__ __launch_bounds__(256) void silumul_kernel(const float* __restrict__ gu,
                                                      bf16* __restrict__ hid,
                                                      const int* __restrict__ cntPtr) {
    long t = blockIdx.x;
    if (cntPtr) {
        int pad = (*cntPtr + 127) & ~127;
        if (t >= pad) return;
    }
    const float* row = gu + t * GUD;
    bf16* h = hid + t * INTERD;
    for (int i = threadIdx.x; i < INTERD; i += 256) {
        float g = row[i], u = row[INTERD + i];
        h[i] = (bf16)(g / (1.f + expf(-g)) * u);
    }
}

// ---------------------------------------------------------------------------
static inline size_t alignup(size_t v) { return (v + 255) & ~(size_t)255; }

extern "C" void kernel_launch(void* const* d_in, const int* in_sizes, int n_in,
                              void* d_out, int out_size, void* d_ws, size_t ws_size,
                              hipStream_t stream) {
    const float* x       = (const float*)d_in[0];
    const float* freq    = (const float*)d_in[1];
    const float* mask    = (const float*)d_in[2];
    const float* w_attn  = (const float*)d_in[3];
    const float* w_ffn   = (const float*)d_in[4];
    const float* W_dq    = (const float*)d_in[5];
    const float* q_c_nrm = (const float*)d_in[6];
    const float* W_uq    = (const float*)d_in[7];
    const float* W_dkv   = (const float*)d_in[8];
    const float* kv_nrm  = (const float*)d_in[9];
    const float* W_ukv   = (const float*)d_in[10];
    const float* W_o     = (const float*)d_in[11];
    const float* W_r     = (const float*)d_in[12];
    const float* Ws_gate = (const float*)d_in[13];
    const float* Ws_up   = (const float*)d_in[14];
    const float* Ws_down = (const float*)d_in[15];
    const float* We_gate = (const float*)d_in[16];
    const float* We_up   = (const float*)d_in[17];
    const float* We_down = (const float*)d_in[18];
    float* out = (float*)d_out;
    char* ws = (char*)d_ws;
    (void)in_sizes; (void)n_in; (void)out_size;

    // ---- workspace layout (~250 MB; known budget >= 378 MB) ----
    size_t o = 0;
    auto alloc = [&](size_t n) { size_t r = o; o += alignup(n); return r; };
    size_t oWslot = alloc((size_t)3072 * QCD * 4);           // 18.9 MB rotating weight slot
    size_t oQfull = alloc((size_t)32 * SEQ * QDIM * 4);
    size_t oKfull = alloc((size_t)32 * SEQ * QDIM * 4);
    size_t oVT    = alloc((size_t)32 * VHD * SEQ * 4);
    size_t oAttn  = alloc((size_t)TOK * HIDD * 4);
    size_t oX2    = alloc((size_t)TOK * HIDD * 4);
    size_t oTbuf  = alloc((size_t)TOK * HIDD * 2);
    size_t oTA    = alloc((size_t)TOK * HIDD * 2);           // gathered rows
    size_t oWts   = alloc((size_t)TOK * 8 * 4);
    size_t oPerm  = alloc((size_t)8 * TOK * 4);
    size_t oCnt   = alloc((size_t)8 * 4);
    size_t oKrope = alloc((size_t)TOK * ROPED * 4);
    // overlay arena: early chain | scores | gu+hid
    size_t zH    = alignup((size_t)TOK * HIDD * 4);
    size_t zCqp  = alignup((size_t)TOK * QCD * 4);
    size_t zCq   = alignup((size_t)TOK * QCD * 4);
    size_t zQp   = alignup((size_t)TOK * 3072 * 4);
    size_t zCkv  = alignup((size_t)TOK * KVDP * 4);
    size_t zKvc  = alignup((size_t)TOK * KVCD * 4);
    size_t zKv   = alignup((size_t)TOK * 4096 * 4);
    size_t chain = zH + zCqp + zCq + zQp + zCkv + zKvc + zKv;
    size_t zScores = alignup((size_t)8 * SEQ * SEQ * 4);
    size_t zGu     = alignup((size_t)TOK * GUD * 4);
    size_t zHid    = alignup((size_t)TOK * INTERD * 2);
    size_t arenaSz = chain;
    if (zScores > arenaSz) arenaSz = zScores;
    if (zGu + zHid > arenaSz) arenaSz = zGu + zHid;
    size_t oArena = alloc(arenaSz);
    if (ws_size < o) return;

    size_t oH    = oArena;
    size_t oCqp  = oH + zH;
    size_t oCq   = oCqp + zCqp;
    size_t oQp   = oCq + zCq;
    size_t oCkv  = oQp + zQp;
    size_t oKvc  = oCkv + zCkv;
    size_t oKv   = oKvc + zKvc;
    size_t oScores = oArena;
    size_t oGu     = oArena;
    size_t oHid    = oArena + zGu;

    float* wslotF = (float*)(ws + oWslot);
    bf16*  wslotB = (bf16*)(ws + oWslot);                           // GU bf16
    bf16*  wslotB2 = (bf16*)(ws + oWslot + (size_t)GUD * HIDD * 2); // down bf16
    float* qfull = (float*)(ws + oQfull);
    float* kfull = (float*)(ws + oKfull);
    float* vT    = (float*)(ws + oVT);
    float* attn  = (float*)(ws + oAttn);
    float* x2    = (float*)(ws + oX2);
    bf16*  tbuf  = (bf16*)(ws + oTbuf);
    bf16*  tA    = (bf16*)(ws + oTA);
    float* wts   = (float*)(ws + oWts);
    int*   perm  = (int*)(ws + oPerm);
    int*   counts = (int*)(ws + oCnt);
    float* krope = (float*)(ws + oKrope);
    float* h     = (float*)(ws + oH);
    float* cqpre = (float*)(ws + oCqp);
    float* cq    = (float*)(ws + oCq);
    float* qpre  = (float*)(ws + oQp);
    float* ckv   = (float*)(ws + oCkv);
    float* kvc   = (float*)(ws + oKvc);
    float* kv    = (float*)(ws + oKv);
    float* scores = (float*)(ws + oScores);
    float* gu    = (float*)(ws + oGu);
    bf16*  hid   = (bf16*)(ws + oHid);

    auto tconvf = [&](const float* src, float* dst, int K, int N, int Npad) {
        dim3 g((Npad + 31) / 32, (K + 31) / 32);
        tconvf_kernel<<<g, 256, 0, stream>>>(src, dst, K, N, Npad);
    };
    auto tconv = [&](const float* src, bf16* dst, int K, int N, int Npad) {
        dim3 g((Npad + 31) / 32, (K + 31) / 32);
        tconv_kernel<<<g, 256, 0, stream>>>(src, dst, K, N, Npad);
    };
    auto gemmS = [&](const float* A, const float* B, float* C, const float* aux,
                     int M, int N, int K, int lda, int ldb, int ldc,
                     long sA, long sB, long sC, int Z, int mode, int auxLd) {
        dim3 g(N / 128, M / 128, Z);
        gemm_f32s_kernel<<<g, 256, 0, stream>>>(A, B, C, aux, K, lda, ldb, ldc, sA, sB, sC, mode, auxLd);
    };
    auto gemmBT = [&](const bf16* A, const bf16* B, void* C,
                      const float* aux, const int* idx, const int* cnt,
                      int M, int N, int K, int lda, int ldb, int ldc, int mode, int auxLd) {
        dim3 g(N / 128, M / 128, 1);
        gemm_bt_kernel<<<g, 256, 0, stream>>>(A, B, C, aux, idx, cnt, K, lda, ldb, ldc, mode, auxLd);
    };

    // ---- attention pipeline (f32 activations, split-fp16 GEMMs) ----
    rmsnorm_kernel<<<TOK, 256, 0, stream>>>(x, w_attn, h, nullptr, nullptr, HIDD);

    tconvf(W_dq, wslotF, HIDD, QCD, QCD);
    gemmS(h, wslotF, cqpre, nullptr, TOK, QCD, HIDD, HIDD, HIDD, QCD, 0, 0, 0, 1, 0, 0);
    rmsnorm_kernel<<<TOK, 256, 0, stream>>>(cqpre, q_c_nrm, cq, nullptr, nullptr, QCD);

    tconvf(W_uq, wslotF, QCD, 3072, 3072);
    gemmS(cq, wslotF, qpre, nullptr, TOK, 3072, QCD, QCD, QCD, 3072, 0, 0, 0, 1, 0, 0);

    tconvf(W_dkv, wslotF, HIDD, KVD, KVDP);
    gemmS(h, wslotF, ckv, nullptr, TOK, KVDP, HIDD, HIDD, HIDD, KVDP, 0, 0, 0, 1, 0, 0);
    kvsplit_kernel<<<TOK, 256, 0, stream>>>(ckv, kv_nrm, freq, kvc, krope);

    tconvf(W_ukv, wslotF, KVCD, 4096, 4096);
    gemmS(kvc, wslotF, kv, nullptr, TOK, 4096, KVCD, KVCD, KVCD, 4096, 0, 0, 0, 1, 0, 0);

    build_q_kernel<<<TOK, 256, 0, stream>>>(qpre, freq, qfull);
    build_k_kernel<<<TOK, 256, 0, stream>>>(kv, krope, kfull, vT);

    const float scale = 1.f / sqrtf((float)QDIM);
    for (int b = 0; b < 2; b++) {
        for (int hc = 0; hc < 2; hc++) {
            int h0 = b * NHEADS + hc * 8;
            gemmS(qfull + (size_t)h0 * SEQ * QDIM, kfull + (size_t)h0 * SEQ * QDIM,
                  scores, nullptr, SEQ, SEQ, QDIM, QDIM, QDIM, SEQ,
                  (long)SEQ * QDIM, (long)SEQ * QDIM, (long)SEQ * SEQ, 8, 0, 0);
            softmax_kernel<<<dim3(SEQ, 8), 256, 0, stream>>>(scores, mask, scale);
            gemmS(scores, vT + (size_t)h0 * VHD * SEQ,
                  attn + (size_t)b * SEQ * HIDD + (size_t)(hc * 8) * VHD, nullptr,
                  SEQ, VHD, SEQ, SEQ, SEQ, HIDD,
                  (long)SEQ * SEQ, (long)VHD * SEQ, (long)VHD, 8, 0, 0);
        }
    }

    tconvf(W_o, wslotF, HIDD, HIDD, HIDD);
    gemmS(attn, wslotF, x2, x, TOK, HIDD, HIDD, HIDD, HIDD, HIDD, 0, 0, 0, 1, 2, HIDD);

    // ---- MoE ----
    rmsnorm_kernel<<<TOK, 256, 0, stream>>>(x2, w_ffn, nullptr, tbuf, out, HIDD); // out = x2
    zero_counts_kernel<<<1, 64, 0, stream>>>(counts);
    router_kernel<<<TOK, 64, 0, stream>>>(x2, w_ffn, W_r, wts, perm, counts);

    // shared experts: dense over all tokens
    for (int e = 0; e < 2; e++) {
        tconv(Ws_gate + (size_t)e * HIDD * INTERD, wslotB, HIDD, INTERD, INTERD);
        tconv(Ws_up   + (size_t)e * HIDD * INTERD, wslotB + (size_t)INTERD * HIDD, HIDD, INTERD, INTERD);
        gemmBT(tbuf, wslotB, gu, nullptr, nullptr, nullptr,
               TOK, GUD, HIDD, HIDD, HIDD, GUD, 0, 0);
        silumul_kernel<<<TOK, 256, 0, stream>>>(gu, hid, nullptr);
        tconv(Ws_down + (size_t)e * INTERD * HIDD, wslotB2, INTERD, HIDD, HIDD);
        gemmBT(hid, wslotB2, out, nullptr, nullptr, nullptr,
               TOK, HIDD, INTERD, INTERD, INTERD, HIDD, 3, 0);
    }
    // routed experts: top-2 sparse (gather -> GEMM over padded count -> scatter)
    for (int e = 0; e < 8; e++) {
        gather_kernel<<<TOK, 256, 0, stream>>>(tbuf, perm + (size_t)e * TOK, counts + e, tA);
        tconv(We_gate + (size_t)e * HIDD * INTERD, wslotB, HIDD, INTERD, INTERD);
        tconv(We_up   + (size_t)e * HIDD * INTERD, wslotB + (size_t)INTERD * HIDD, HIDD, INTERD, INTERD);
        gemmBT(tA, wslotB, gu, nullptr, nullptr, counts + e,
               TOK, GUD, HIDD, HIDD, HIDD, GUD, 0, 0);
        silumul_kernel<<<TOK, 256, 0, stream>>>(gu, hid, counts + e);
        tconv(We_down + (size_t)e * INTERD * HIDD, wslotB2, INTERD, HIDD, HIDD);
        gemmBT(hid, wslotB2, out, wts + e, perm + (size_t)e * TOK, counts + e,
               TOK, HIDD, INTERD, INTERD, INTERD, HIDD, 5, 8);
    }
}